// Round 5
// baseline (407.220 us; speedup 1.0000x reference)
//
#include <hip/hip_runtime.h>

// AttentionHead  B=4, T=2048, C=1024, HEAD=2048, fp32 in/out.
// Round 8: two schedule-engineering rounds (r6/r7) failed to overlap LDS and
// MFMA because all waves share one barrier domain (1 block/CU at 128KB LDS).
// Rebuild the core around TLP instead (m97/m114 mechanism): BM=256/BN=128
// (qk,o) or 128x128 (s), 4 waves of 128x64 / 64x64, BK=32, dbuf LDS 48/32KB,
// __launch_bounds__(256,2) -> 2 independent blocks/CU; one __syncthreads per
// K-tile (auto vmcnt(0) drains the stage issued a full iter earlier).
// BK=32 swizzle: 64B rows; byte ^= ((row>>1)&3)<<4 on 16B slots ->
// 64 lanes cover 64 distinct 16B regions = conflict-free; staging source
// pre-swizzle (ln&3)*8 ^ ((ln>>3)&3)*8. gemm_s retiled to 128^2 -> 544
// blocks (was 144/256 CUs). qk gets bijective XCD swizzle.

#define T_    2048
#define C_    1024
#define B_    4
#define NQK   4096
#define SCALE 0.03125f   // C^-0.5 = 1/32 exactly

typedef __attribute__((ext_vector_type(4))) float floatx4;
typedef __attribute__((ext_vector_type(8))) short short8;
typedef __attribute__((ext_vector_type(8))) unsigned short ushortx8;

__device__ __forceinline__ unsigned short f2bf(float f) {
  unsigned int u = __float_as_uint(f);
  unsigned int r = (u + 0x7fffu + ((u >> 16) & 1u)) >> 16;  // RNE
  return (unsigned short)r;
}

// ---------------------------------------------------------------- cast x
__global__ void cast_x_kernel(const float* __restrict__ x, ushort* __restrict__ xbf) {
  int i = blockIdx.x * 256 + threadIdx.x;          // over N/4 = 2097152
  float4 v = ((const float4*)x)[i];
  ushort4 o;
  o.x = f2bf(v.x); o.y = f2bf(v.y); o.z = f2bf(v.z); o.w = f2bf(v.w);
  ((ushort4*)xbf)[i] = o;
}

// ------------------------------------------- cast + transpose W -> WtT[n][k]
__global__ void wcast_t_kernel(const float* __restrict__ Wq, const float* __restrict__ Wk,
                               const float* __restrict__ Wv, ushort* __restrict__ WtT) {
  int k0 = blockIdx.x * 32;           // over C=1024
  int n0 = blockIdx.y * 32;           // over 6144
  const float* W = (n0 < 2048) ? Wq : (n0 < 4096 ? Wk : Wv);
  int nl0 = n0 & 2047;
  __shared__ ushort tile[32][33];
  int tx = threadIdx.x, ty = threadIdx.y;
  for (int r = ty; r < 32; r += 8)
    tile[r][tx] = f2bf(W[(size_t)(k0 + r) * 2048 + nl0 + tx]);
  __syncthreads();
  for (int r = ty; r < 32; r += 8)
    WtT[(size_t)(n0 + r) * 1024 + k0 + tx] = tile[tx][r];
}

// ---------------------------------------------------------------- bias concat
__global__ void bias_cat_kernel(const float* __restrict__ bq, const float* __restrict__ bk,
                                const float* __restrict__ bv, float* __restrict__ bcat) {
  int i = blockIdx.x * 256 + threadIdx.x;
  if (i < 6144) {
    const float* s = (i < 2048) ? bq : (i < 4096 ? bk : bv);
    bcat[i] = s[i & 2047];
  }
}

#define MFMA16(a, b, c) __builtin_amdgcn_mfma_f32_16x16x32_bf16((a), (b), (c), 0, 0, 0)

#define GLDS16(gsrc, ldst)                                                                       \
  __builtin_amdgcn_global_load_lds((const __attribute__((address_space(1))) unsigned int*)(gsrc), \
                                   (__attribute__((address_space(3))) unsigned int*)(ldst), 16, 0, 0)

// ------------------------------------------------------- GEMM core (m97 BT)
// kept for gemm_v (128x128 tile, transposed epilogue)
__device__ __forceinline__ void stage128x32(const ushort* g, int ld, char* lds,
                                            int wave, int lane) {
#pragma unroll
  for (int c = 0; c < 2; ++c) {
    int chunk = wave + 4 * c;                       // 8 chunks of 16 rows
    const ushort* gaddr = g + (size_t)(chunk * 16 + (lane >> 2)) * ld + (lane & 3) * 8;
    char* laddr = lds + chunk * 1024;               // wave-uniform
    GLDS16(gaddr, laddr);
  }
}

__device__ __forceinline__ void gemm_core(const ushort* A, int lda,
                                          const ushort* Bm, int ldb, int ksteps,
                                          char* ldsA, char* ldsB, floatx4 acc[4][4]) {
  int tid = threadIdx.x;
  int wave = tid >> 6, lane = tid & 63;
  int wm = wave >> 1, wn = wave & 1;
  int koff2 = ((lane >> 4) * 8) * 2;   // byte offset of k-fragment
  int rbase = lane & 15;
  for (int s = 0; s < ksteps; ++s) {
    __syncthreads();                              // LDS reads of prev iter done
    stage128x32(A + s * 32, lda, ldsA, wave, lane);
    stage128x32(Bm + s * 32, ldb, ldsB, wave, lane);
    __syncthreads();                              // vmcnt drain before reads
    short8 af[4], bf[4];
#pragma unroll
    for (int i = 0; i < 4; ++i) {
      af[i] = *(const short8*)(ldsA + (wm * 64 + i * 16 + rbase) * 64 + koff2);
      bf[i] = *(const short8*)(ldsB + (wn * 64 + i * 16 + rbase) * 64 + koff2);
    }
#pragma unroll
    for (int i = 0; i < 4; ++i)
#pragma unroll
      for (int j = 0; j < 4; ++j)
        acc[i][j] = MFMA16(af[i], bf[j], acc[i][j]);
  }
}

// ===================== BK=32 TLP GEMM core (BT, bf16) ===========================
// Block = 256 thr = 4 waves (2x2), wave-tile WM x WN, BM=2WM, BN=2WN, BK=32.
// LDS dbuf: [bufp: A(BM x 32) | B(BN x 32)] x2, rows 64B, 16B-slot swizzle
// slot_phys = slot_log ^ ((row>>1)&3). Staging: linear LDS dest (gload_lds),
// inverse-swizzled global source col = ((ln&3)*8) ^ (((ln>>3)&3)*8) ushorts.
// Loop: one __syncthreads per K-tile; its auto vmcnt(0) drains the stage
// issued in the PREVIOUS iter (full iter of latency slack); stage(s+1) into
// buf p^1 is WAR-safe (p^1's readers ran in iter s-1, before this barrier).
// Overlap comes from 2 blocks/CU in independent barrier domains (launch_bounds).

template <int LD, int NCH>
__device__ __forceinline__ void stage_tile(const ushort* g, char* ldsbase, int wave, int ln) {
#pragma unroll
  for (int i = 0; i < NCH / 4; ++i) {
    int c = wave + 4 * i;
    GLDS16(g + (size_t)(c * 16 + (ln >> 2)) * LD, ldsbase + c * 1024);
  }
}

template <int WM, int WN, int LDA, int LDB>
__device__ __forceinline__ void gemm_bk32(const ushort* __restrict__ Ap,
                                          const ushort* __restrict__ Bp,
                                          char* lds, int nk,
                                          floatx4 (&acc)[WM / 16][WN / 16]) {
  constexpr int BM = 2 * WM, BN = 2 * WN;
  constexpr int BUF = (BM + BN) * 64;              // bytes per buffer
  int tid = threadIdx.x, wave = tid >> 6, ln = tid & 63;
  int wm = wave >> 1, wn = wave & 1, ln15 = ln & 15;
  int lnoff = ln15 * 64 + (((ln >> 4) ^ ((ln15 >> 1) & 3)) << 4);
  int srcCol = ((ln & 3) * 8) ^ (((ln >> 3) & 3) * 8);
  stage_tile<LDA, BM / 16>(Ap + srcCol, lds, wave, ln);
  stage_tile<LDB, BN / 16>(Bp + srcCol, lds + BM * 64, wave, ln);
  int p = 0;
  for (int s = 0; s < nk; ++s) {
    __syncthreads();                               // drains vmcnt: buf p ready
    if (s + 1 < nk) {
      stage_tile<LDA, BM / 16>(Ap + (s + 1) * 32 + srcCol, lds + (p ^ 1) * BUF, wave, ln);
      stage_tile<LDB, BN / 16>(Bp + (s + 1) * 32 + srcCol, lds + (p ^ 1) * BUF + BM * 64, wave, ln);
    }
    const char* La = lds + p * BUF + (wm * WM) * 64;
    const char* Lb = lds + p * BUF + BM * 64 + (wn * WN) * 64;
    short8 af[WM / 16], bf[WN / 16];
#pragma unroll
    for (int mi = 0; mi < WM / 16; ++mi) af[mi] = *(const short8*)(La + mi * 1024 + lnoff);
#pragma unroll
    for (int nj = 0; nj < WN / 16; ++nj) bf[nj] = *(const short8*)(Lb + nj * 1024 + lnoff);
#pragma unroll
    for (int mi = 0; mi < WM / 16; ++mi)
#pragma unroll
      for (int nj = 0; nj < WN / 16; ++nj)
        acc[mi][nj] = MFMA16(af[mi], bf[nj], acc[mi][nj]);
    p ^= 1;
  }
}

// ------------------------------------------- GEMM: Q,K projection (256x128)
__global__ __launch_bounds__(256, 2) void gemm_qk(const ushort* __restrict__ xbf,
                                                  const ushort* __restrict__ WtT,
                                                  const float* __restrict__ bcat,
                                                  ushort* __restrict__ QK) {
  __shared__ __align__(16) char lds[49152];
  int bid = blockIdx.x;                            // 1024 blocks; XCD-bijective swizzle
  int swz = (bid & 7) * 128 + (bid >> 3);
  int tm = swz & 31, tn = swz >> 5;                // tm over M=8192/256, tn over N=4096/128
  floatx4 acc[8][4];
#pragma unroll
  for (int i = 0; i < 8; ++i)
#pragma unroll
    for (int j = 0; j < 4; ++j) acc[i][j] = (floatx4){0.f, 0.f, 0.f, 0.f};
  gemm_bk32<128, 64, 1024, 1024>(xbf + (size_t)tm * 256 * 1024,
                                 WtT + (size_t)tn * 128 * 1024, lds, 32, acc);
  int tid = threadIdx.x, wave = tid >> 6, ln = tid & 63;
  int wm = wave >> 1, wn = wave & 1, ln15 = ln & 15;
  int colb = ln15, rowq = (ln >> 4) * 4;
  int colbase = tn * 128 + wn * 64 + colb;
  float bias[4];
#pragma unroll
  for (int nj = 0; nj < 4; ++nj) bias[nj] = bcat[colbase + nj * 16];
#pragma unroll
  for (int mi = 0; mi < 8; ++mi) {
    int row = tm * 256 + wm * 128 + mi * 16 + rowq;
#pragma unroll
    for (int r = 0; r < 4; ++r) {
      ushort* qrow = QK + (size_t)(row + r) * NQK;
#pragma unroll
      for (int nj = 0; nj < 4; ++nj)
        qrow[colbase + nj * 16] = f2bf(acc[mi][nj][r] + bias[nj]);
    }
  }
}

// ------------------------------------------------- GEMM: S = Q*K^T (128x128)
__global__ __launch_bounds__(256, 2) void gemm_s(const ushort* __restrict__ QK,
                                                 float* __restrict__ S) {
  int l = blockIdx.x, b = blockIdx.y;              // l in [0,136): tn <= tm, 128-gran
  int tm = (int)((sqrtf(8.f * l + 1.f) - 1.f) * 0.5f);
  while ((tm + 1) * (tm + 2) / 2 <= l) ++tm;
  while (tm * (tm + 1) / 2 > l) --tm;
  int tn = l - tm * (tm + 1) / 2;
  __shared__ __align__(16) char lds[32768];
  floatx4 acc[4][4];
#pragma unroll
  for (int i = 0; i < 4; ++i)
#pragma unroll
    for (int j = 0; j < 4; ++j) acc[i][j] = (floatx4){0.f, 0.f, 0.f, 0.f};
  const ushort* Ap = QK + (size_t)b * T_ * NQK + (size_t)tm * 128 * NQK;         // Q rows
  const ushort* Bp = QK + (size_t)b * T_ * NQK + (size_t)tn * 128 * NQK + 2048;  // K rows
  gemm_bk32<64, 64, NQK, NQK>(Ap, Bp, lds, 64, acc);
  float* Sb = S + (size_t)b * T_ * T_;
  int tid = threadIdx.x, wave = tid >> 6, ln = tid & 63;
  int wm = wave >> 1, wn = wave & 1, ln15 = ln & 15;
  int colb = ln15, rowq = (ln >> 4) * 4;
  int colbase = tn * 128 + wn * 64 + colb;
#pragma unroll
  for (int mi = 0; mi < 4; ++mi) {
    int row = tm * 128 + wm * 64 + mi * 16 + rowq;
#pragma unroll
    for (int r = 0; r < 4; ++r) {
      float* srow = Sb + (size_t)(row + r) * T_;
#pragma unroll
      for (int nj = 0; nj < 4; ++nj)
        srow[colbase + nj * 16] = acc[mi][nj][r] * SCALE;
    }
  }
}

// ------------------------------------------------ GEMM: O = P*V (256x128)
__global__ __launch_bounds__(256, 2) void gemm_o(const ushort* __restrict__ P,
                                                 const ushort* __restrict__ Vt,
                                                 float* __restrict__ O) {
  int tn = blockIdx.x, tm = 7 - blockIdx.y, b = blockIdx.z;  // longest-first
  __shared__ __align__(16) char lds[49152];
  floatx4 acc[8][4];
#pragma unroll
  for (int i = 0; i < 8; ++i)
#pragma unroll
    for (int j = 0; j < 4; ++j) acc[i][j] = (floatx4){0.f, 0.f, 0.f, 0.f};
  const ushort* Ap = P + (size_t)b * T_ * T_ + (size_t)tm * 256 * T_;
  const ushort* Bp = Vt + (size_t)b * T_ * T_ + (size_t)tn * 128 * T_;
  gemm_bk32<128, 64, T_, T_>(Ap, Bp, lds, (tm + 1) * 8, acc);   // k_end=(tm+1)*256
  float* Ob = O + (size_t)b * T_ * T_;
  int tid = threadIdx.x, wave = tid >> 6, ln = tid & 63;
  int wm = wave >> 1, wn = wave & 1, ln15 = ln & 15;
  int colb = ln15, rowq = (ln >> 4) * 4;
  int colbase = tn * 128 + wn * 64 + colb;
#pragma unroll
  for (int mi = 0; mi < 8; ++mi) {
    int row = tm * 256 + wm * 128 + mi * 16 + rowq;
#pragma unroll
    for (int r = 0; r < 4; ++r) {
      float* orow = Ob + (size_t)(row + r) * T_;
#pragma unroll
      for (int nj = 0; nj < 4; ++nj)
        orow[colbase + nj * 16] = acc[mi][nj][r];
    }
  }
}

// --------------------------- GEMM: V projection, writes Vt[b][h][s] directly
__global__ __launch_bounds__(256) void gemm_v(const ushort* __restrict__ xbf,
                                              const ushort* __restrict__ WtT,
                                              const float* __restrict__ bcat,
                                              ushort* __restrict__ Vt) {
  __shared__ __align__(16) char lds[128 * 136 * 2];   // 34816 B; first 16KB = staging
  char* ldsA = lds;
  char* ldsB = lds + 8192;
  int tm = blockIdx.x, tn = blockIdx.y;          // tn in [0,16)
  floatx4 acc[4][4];
#pragma unroll
  for (int i = 0; i < 4; ++i)
#pragma unroll
    for (int j = 0; j < 4; ++j) acc[i][j] = (floatx4){0.f, 0.f, 0.f, 0.f};
  gemm_core(xbf + (size_t)tm * 128 * C_, C_, WtT + (size_t)(32 + tn) * 128 * C_, C_,
            C_ / 32, ldsA, ldsB, acc);
  int tid = threadIdx.x, wave = tid >> 6, lane = tid & 63;
  int wm = wave >> 1, wn = wave & 1;
  int colb = lane & 15, rowq = (lane >> 4) * 4;
  __syncthreads();                               // staging reads all consumed
  ushort* tileT = (ushort*)lds;                  // [h_local][s_local], stride 136
#pragma unroll
  for (int j = 0; j < 4; ++j) {
    int h = wn * 64 + j * 16 + colb;
    float bv = bcat[4096 + tn * 128 + h];
#pragma unroll
    for (int i = 0; i < 4; ++i) {
      int s = wm * 64 + i * 16 + rowq;
      ushort4 o4;
      o4.x = f2bf(acc[i][j][0] + bv);
      o4.y = f2bf(acc[i][j][1] + bv);
      o4.z = f2bf(acc[i][j][2] + bv);
      o4.w = f2bf(acc[i][j][3] + bv);
      *(ushort4*)(tileT + h * 136 + s) = o4;
    }
  }
  __syncthreads();
  int b = tm >> 4, sbase = (tm & 15) * 128;
  int hr = tid >> 4, sc = (tid & 15) * 8;
#pragma unroll
  for (int it = 0; it < 8; ++it) {
    int h = it * 16 + hr;
    ushortx8 v = *(const ushortx8*)(tileT + h * 136 + sc);
    *(ushortx8*)(Vt + ((size_t)b * T_ + tn * 128 + h) * T_ + sbase + sc) = v;
  }
}

// ------------------------------------------------------------ causal softmax
__global__ __launch_bounds__(256) void softmax_causal(const float* __restrict__ S,
                                                      ushort* __restrict__ P) {
  int t = blockIdx.x, b = blockIdx.y;
  int tid = threadIdx.x;
  const float* srow = S + ((size_t)b * T_ + t) * T_;
  ushort* prow = P + ((size_t)b * T_ + t) * T_;
  int band = ((t >> 8) + 1) << 8;    // round_up(t+1, 256) == gemm_o k_end
  float xv[8];
  float m = -INFINITY;
#pragma unroll
  for (int c = 0; c < 2; ++c) {
    int s0 = c * 1024 + tid * 4;
    float* xs = xv + c * 4;
    if (s0 < band) {
      float4 v = *(const float4*)(srow + s0);
      xs[0] = (s0 + 0 <= t) ? v.x : -INFINITY;  // scale applied in gemm_s
      xs[1] = (s0 + 1 <= t) ? v.y : -INFINITY;
      xs[2] = (s0 + 2 <= t) ? v.z : -INFINITY;
      xs[3] = (s0 + 3 <= t) ? v.w : -INFINITY;
      m = fmaxf(fmaxf(fmaxf(xs[0], xs[1]), fmaxf(xs[2], xs[3])), m);
    } else {
      xs[0] = xs[1] = xs[2] = xs[3] = -INFINITY;
    }
  }
  __shared__ float sm4[4];
  int wid = tid >> 6, ln = tid & 63;
#pragma unroll
  for (int o = 32; o; o >>= 1) m = fmaxf(m, __shfl_xor(m, o));
  if (ln == 0) sm4[wid] = m;
  __syncthreads();
  m = fmaxf(fmaxf(sm4[0], sm4[1]), fmaxf(sm4[2], sm4[3]));
  __syncthreads();
  float sum = 0.f;
#pragma unroll
  for (int k = 0; k < 8; ++k) { xv[k] = __expf(xv[k] - m); sum += xv[k]; }
#pragma unroll
  for (int o = 32; o; o >>= 1) sum += __shfl_xor(sum, o);
  if (ln == 0) sm4[wid] = sum;
  __syncthreads();
  sum = sm4[0] + sm4[1] + sm4[2] + sm4[3];
  float inv = 1.0f / sum;
#pragma unroll
  for (int c = 0; c < 2; ++c) {
    int s0 = c * 1024 + tid * 4;
    if (s0 < band) {
      ushort4 o4;
      o4.x = f2bf(xv[c * 4 + 0] * inv);
      o4.y = f2bf(xv[c * 4 + 1] * inv);
      o4.z = f2bf(xv[c * 4 + 2] * inv);
      o4.w = f2bf(xv[c * 4 + 3] * inv);
      *(ushort4*)(prow + s0) = o4;
    }
  }
}

// ---------------------------------------------------------------- launcher
extern "C" void kernel_launch(void* const* d_in, const int* in_sizes, int n_in,
                              void* d_out, int out_size, void* d_ws, size_t ws_size,
                              hipStream_t stream) {
  (void)in_sizes; (void)n_in; (void)out_size; (void)ws_size;
  const float* x  = (const float*)d_in[0];
  const float* Wq = (const float*)d_in[1];
  const float* bq = (const float*)d_in[2];
  const float* Wk = (const float*)d_in[3];
  const float* bk = (const float*)d_in[4];
  const float* Wv = (const float*)d_in[5];
  const float* bv = (const float*)d_in[6];

  char* ws = (char*)d_ws;
  ushort* xbf  = (ushort*)(ws + 0);           // 16,777,216 B
  ushort* WtT  = (ushort*)(ws + 16777216);    // 12,582,912 B
  float*  bcat = (float*) (ws + 29360128);    //     24,576 B
  ushort* QK   = (ushort*)(ws + 29384704);    // 67,108,864 B  [8192][4096]
  ushort* P    = (ushort*)(ws + 96493568);    // 33,554,432 B
  ushort* Vt   = (ushort*)(ws + 130048000);   // 33,554,432 B  (end ~156 MiB)

  float* S = (float*)d_out;   // S scratch lives in d_out, later overwritten by O
  float* O = (float*)d_out;

  cast_x_kernel  <<<8192, 256, 0, stream>>>(x, xbf);
  wcast_t_kernel <<<dim3(32, 192), dim3(32, 8), 0, stream>>>(Wq, Wk, Wv, WtT);
  bias_cat_kernel<<<24, 256, 0, stream>>>(bq, bk, bv, bcat);
  gemm_qk        <<<1024, 256, 0, stream>>>(xbf, WtT, bcat, QK);
  gemm_v         <<<dim3(64, 16), 256, 0, stream>>>(xbf, WtT, bcat, Vt);
  gemm_s         <<<dim3(136, 4), 256, 0, stream>>>(QK, S);
  softmax_causal <<<dim3(2048, 4), 256, 0, stream>>>(S, P);
  gemm_o         <<<dim3(16, 8, 4), 256, 0, stream>>>(P, Vt, O);
}

// Round 6
// 335.207 us; speedup vs baseline: 1.2148x; 1.2148x over previous
//
#include <hip/hip_runtime.h>

// AttentionHead  B=4, T=2048, C=1024, HEAD=2048, fp32 in/out.
// Round 9: revert r8's BK=32 experiment (regression: smaller tiles halved
// arithmetic intensity, FETCH 49->135MB, 808 TF). Base = r7 (349.6us).
// New: fuse gemm_s256 (144 blocks, 44% of CUs idle) with gemm_v (retiled to
// the 256^2 pair core, 256 blocks) into ONE kernel gemm_sv, S-blocks first:
// V fills the idle CUs -> makespan ~76us vs 72+47 serial. V epilogue
// transposes through LDS (free after K-loop) with byte_s ^= (h&31)<<4
// swizzle; K-order identical to old gemm_v -> bit-identical Vt.

#define T_    2048
#define C_    1024
#define B_    4
#define NQK   4096
#define SCALE 0.03125f   // C^-0.5 = 1/32 exactly

typedef __attribute__((ext_vector_type(4))) float floatx4;
typedef __attribute__((ext_vector_type(8))) short short8;
typedef __attribute__((ext_vector_type(8))) unsigned short ushortx8;

__device__ __forceinline__ unsigned short f2bf(float f) {
  unsigned int u = __float_as_uint(f);
  unsigned int r = (u + 0x7fffu + ((u >> 16) & 1u)) >> 16;  // RNE
  return (unsigned short)r;
}

// ---------------------------------------------------------------- cast x
__global__ void cast_x_kernel(const float* __restrict__ x, ushort* __restrict__ xbf) {
  int i = blockIdx.x * 256 + threadIdx.x;          // over N/4 = 2097152
  float4 v = ((const float4*)x)[i];
  ushort4 o;
  o.x = f2bf(v.x); o.y = f2bf(v.y); o.z = f2bf(v.z); o.w = f2bf(v.w);
  ((ushort4*)xbf)[i] = o;
}

// ------------------------------------------- cast + transpose W -> WtT[n][k]
__global__ void wcast_t_kernel(const float* __restrict__ Wq, const float* __restrict__ Wk,
                               const float* __restrict__ Wv, ushort* __restrict__ WtT) {
  int k0 = blockIdx.x * 32;           // over C=1024
  int n0 = blockIdx.y * 32;           // over 6144
  const float* W = (n0 < 2048) ? Wq : (n0 < 4096 ? Wk : Wv);
  int nl0 = n0 & 2047;
  __shared__ ushort tile[32][33];
  int tx = threadIdx.x, ty = threadIdx.y;
  for (int r = ty; r < 32; r += 8)
    tile[r][tx] = f2bf(W[(size_t)(k0 + r) * 2048 + nl0 + tx]);
  __syncthreads();
  for (int r = ty; r < 32; r += 8)
    WtT[(size_t)(n0 + r) * 1024 + k0 + tx] = tile[tx][r];
}

// ---------------------------------------------------------------- bias concat
__global__ void bias_cat_kernel(const float* __restrict__ bq, const float* __restrict__ bk,
                                const float* __restrict__ bv, float* __restrict__ bcat) {
  int i = blockIdx.x * 256 + threadIdx.x;
  if (i < 6144) {
    const float* s = (i < 2048) ? bq : (i < 4096 ? bk : bv);
    bcat[i] = s[i & 2047];
  }
}

// ===================== 256x256 pair-pipelined GEMM core (BT, bf16) ==============
// Geometry: BM=BN=256, BK=64, 8 waves (wm=wave>>2, wn=wave&3), per-wave output
// 128x64 (acc[8][4] of 16x16 frags). LDS 128 KiB:
//   A: buf0 @0,16384; buf1 @32768,49152   (region = 128 rows x 64 cols bf16)
//   B: buf0 @65536,81920; buf1 @98304,114688
// Swizzle: physical byte-in-row = logical ^ ((row&7)<<4) (conflict-free, r5).
// Pair schedule per iter (tiles t=buf0, t+1=buf1), one s_barrier per pair:
//   pairA: read A-lo(t)+B(all,t), stage (t+1,A)->buf1A,  32 MFMA (m-lo)
//   pairB: read A-hi(t),          stage (t+2,B)->buf0B,  32 MFMA (m-hi)
//          gate vmcnt(4) [buf1A + prev buf1B confirmed]
//   pairC: read A-lo(t+1)+B(t+1), stage (t+2,A)->buf0A,  32 MFMA (m-lo)
//   pairD: read A-hi(t+1),        stage (t+3,B)->buf1B,  32 MFMA (m-hi)
//          gate vmcnt(4) [all buf0 for next iter confirmed]

#define MFMA16(a, b, c) __builtin_amdgcn_mfma_f32_16x16x32_bf16((a), (b), (c), 0, 0, 0)

#define GLDS16(gsrc, ldst)                                                                       \
  __builtin_amdgcn_global_load_lds((const __attribute__((address_space(1))) unsigned int*)(gsrc), \
                                   (__attribute__((address_space(3))) unsigned int*)(ldst), 16, 0, 0)

template <int LD>
__device__ __forceinline__ void stage_half(const ushort* gsrc, char* ldst) {
  GLDS16(gsrc, ldst);
  GLDS16(gsrc + 8 * LD, ldst + 1024);
}

#define BARX() do {                                        \
  __builtin_amdgcn_sched_barrier(0);                       \
  __builtin_amdgcn_s_barrier();                            \
  __builtin_amdgcn_sched_barrier(0);                       \
} while (0)

template <int LDA, int LDB>
__device__ __forceinline__ void prologue256(const ushort* Ap, const ushort* Bp,
                                            char* lds, int wave, int srcOffA, int srcOffB) {
  stage_half<LDA>(Ap + srcOffA,                     lds + wave * 2048);
  stage_half<LDA>(Ap + 128 * LDA + srcOffA,         lds + 16384 + wave * 2048);
  stage_half<LDB>(Bp + srcOffB,                     lds + 65536 + wave * 2048);
  stage_half<LDB>(Bp + 128 * LDB + srcOffB,         lds + 81920 + wave * 2048);
  stage_half<LDB>(Bp + 64 + srcOffB,                lds + 98304 + wave * 2048);
  stage_half<LDB>(Bp + 64 + 128 * LDB + srcOffB,    lds + 114688 + wave * 2048);
  __builtin_amdgcn_sched_barrier(0);
  asm volatile("s_waitcnt vmcnt(4)" ::: "memory");
  BARX();
}

template <int LDA, int LDB, bool TAIL>
__device__ __forceinline__ void iter256(const ushort* __restrict__ Ap,
                                        const ushort* __restrict__ Bp,
                                        char* lds, int kt0, int wave, int wm, int wn,
                                        int srcOffA, int srcOffB, int lnoff0,
                                        floatx4 (&acc)[8][4]) {
  char* rA0 = lds + wm * 16384;                    // tile kt0   (buf0) A, this wave
  char* rA1 = rA0 + 32768;                         // tile kt0+1 (buf1) A
  char* rB0 = lds + 65536 + (wn >> 1) * 16384 + (wn & 1) * 8192;
  char* rB1 = rB0 + 32768;
  const ushort* sA1 = Ap + (kt0 + 1) * 64 + srcOffA;
  const ushort* sA2 = Ap + (kt0 + 2) * 64 + srcOffA;
  const ushort* sB2 = Bp + (kt0 + 2) * 64 + srcOffB;
  const ushort* sB3 = Bp + (kt0 + 3) * 64 + srcOffB;
  const int lnoff1 = lnoff0 ^ 64;                  // second k-frag (swz carries bit6)
  short8 af[4][2], b4[4][2];

  // ==== pair A: tile kt0, m-lo rows x all n ============================
#pragma unroll
  for (int mi = 0; mi < 4; ++mi) {
    af[mi][0] = *(const short8*)(rA0 + mi * 2048 + lnoff0);
    af[mi][1] = *(const short8*)(rA0 + mi * 2048 + lnoff1);
  }
#pragma unroll
  for (int nj = 0; nj < 4; ++nj) {
    b4[nj][0] = *(const short8*)(rB0 + nj * 2048 + lnoff0);
    b4[nj][1] = *(const short8*)(rB0 + nj * 2048 + lnoff1);
  }
  stage_half<LDA>(sA1, lds + 32768 + wave * 2048);
  stage_half<LDA>(sA1 + 128 * LDA, lds + 49152 + wave * 2048);
  __builtin_amdgcn_s_setprio(1);
#pragma unroll
  for (int mi = 0; mi < 4; ++mi)
#pragma unroll
    for (int nj = 0; nj < 4; ++nj) {
      acc[mi][nj] = MFMA16(af[mi][0], b4[nj][0], acc[mi][nj]);
      acc[mi][nj] = MFMA16(af[mi][1], b4[nj][1], acc[mi][nj]);
    }
  __builtin_amdgcn_s_setprio(0);
  BARX();

  // ==== pair B: tile kt0, m-hi rows ====================================
#pragma unroll
  for (int mi = 0; mi < 4; ++mi) {
    af[mi][0] = *(const short8*)(rA0 + (4 + mi) * 2048 + lnoff0);
    af[mi][1] = *(const short8*)(rA0 + (4 + mi) * 2048 + lnoff1);
  }
  if constexpr (!TAIL) {
    stage_half<LDB>(sB2, lds + 65536 + wave * 2048);
    stage_half<LDB>(sB2 + 128 * LDB, lds + 81920 + wave * 2048);
  }
  __builtin_amdgcn_s_setprio(1);
#pragma unroll
  for (int mi = 0; mi < 4; ++mi)
#pragma unroll
    for (int nj = 0; nj < 4; ++nj) {
      acc[4 + mi][nj] = MFMA16(af[mi][0], b4[nj][0], acc[4 + mi][nj]);
      acc[4 + mi][nj] = MFMA16(af[mi][1], b4[nj][1], acc[4 + mi][nj]);
    }
  __builtin_amdgcn_s_setprio(0);
  __builtin_amdgcn_sched_barrier(0);
  if constexpr (TAIL) asm volatile("s_waitcnt vmcnt(0)" ::: "memory");
  else                asm volatile("s_waitcnt vmcnt(4)" ::: "memory");
  BARX();

  // ==== pair C: tile kt0+1, m-lo rows x all n ==========================
#pragma unroll
  for (int mi = 0; mi < 4; ++mi) {
    af[mi][0] = *(const short8*)(rA1 + mi * 2048 + lnoff0);
    af[mi][1] = *(const short8*)(rA1 + mi * 2048 + lnoff1);
  }
#pragma unroll
  for (int nj = 0; nj < 4; ++nj) {
    b4[nj][0] = *(const short8*)(rB1 + nj * 2048 + lnoff0);
    b4[nj][1] = *(const short8*)(rB1 + nj * 2048 + lnoff1);
  }
  if constexpr (!TAIL) {
    stage_half<LDA>(sA2, lds + wave * 2048);
    stage_half<LDA>(sA2 + 128 * LDA, lds + 16384 + wave * 2048);
  }
  __builtin_amdgcn_s_setprio(1);
#pragma unroll
  for (int mi = 0; mi < 4; ++mi)
#pragma unroll
    for (int nj = 0; nj < 4; ++nj) {
      acc[mi][nj] = MFMA16(af[mi][0], b4[nj][0], acc[mi][nj]);
      acc[mi][nj] = MFMA16(af[mi][1], b4[nj][1], acc[mi][nj]);
    }
  __builtin_amdgcn_s_setprio(0);
  BARX();

  // ==== pair D: tile kt0+1, m-hi rows ==================================
#pragma unroll
  for (int mi = 0; mi < 4; ++mi) {
    af[mi][0] = *(const short8*)(rA1 + (4 + mi) * 2048 + lnoff0);
    af[mi][1] = *(const short8*)(rA1 + (4 + mi) * 2048 + lnoff1);
  }
  if constexpr (!TAIL) {
    stage_half<LDB>(sB3, lds + 98304 + wave * 2048);
    stage_half<LDB>(sB3 + 128 * LDB, lds + 114688 + wave * 2048);
  }
  __builtin_amdgcn_s_setprio(1);
#pragma unroll
  for (int mi = 0; mi < 4; ++mi)
#pragma unroll
    for (int nj = 0; nj < 4; ++nj) {
      acc[4 + mi][nj] = MFMA16(af[mi][0], b4[nj][0], acc[4 + mi][nj]);
      acc[4 + mi][nj] = MFMA16(af[mi][1], b4[nj][1], acc[4 + mi][nj]);
    }
  __builtin_amdgcn_s_setprio(0);
  __builtin_amdgcn_sched_barrier(0);
  if constexpr (!TAIL) asm volatile("s_waitcnt vmcnt(4)" ::: "memory");
  BARX();
}

// Per-thread addressing for the 256x256 core.
struct Addr256 {
  int wave, wm, wn, ln, ln15, lnoff0;
};
__device__ __forceinline__ Addr256 addr256() {
  Addr256 a;
  int tid = threadIdx.x;
  a.wave = tid >> 6; a.ln = tid & 63;
  a.wm = a.wave >> 2; a.wn = a.wave & 3;
  a.ln15 = a.ln & 15;
  a.lnoff0 = a.ln15 * 128 + (((a.ln >> 4) * 16) ^ ((a.ln15 & 7) << 4));
  return a;
}
template <int LD>
__device__ __forceinline__ int srcOff256(int wave, int ln) {
  return (wave * 16 + (ln >> 3)) * LD + (((ln & 7) * 8) ^ ((ln >> 3) << 3));
}

// ------------------------------------------- GEMM: Q,K projection (ld=1024)
__global__ __launch_bounds__(512) void gemm_qk256(const ushort* __restrict__ xbf,
                                                  const ushort* __restrict__ WtT,
                                                  const float* __restrict__ bcat,
                                                  ushort* __restrict__ QK) {
  __shared__ __align__(16) char lds[131072];
  int tm = blockIdx.x, tn = blockIdx.y;            // (32, 16)
  Addr256 a = addr256();
  int srcOff = srcOff256<1024>(a.wave, a.ln);
  const ushort* Ap = xbf + (size_t)tm * 256 * 1024;
  const ushort* Bp = WtT + (size_t)tn * 256 * 1024;
  floatx4 acc[8][4];
#pragma unroll
  for (int i = 0; i < 8; ++i)
#pragma unroll
    for (int j = 0; j < 4; ++j) acc[i][j] = (floatx4){0.f, 0.f, 0.f, 0.f};

  prologue256<1024, 1024>(Ap, Bp, lds, a.wave, srcOff, srcOff);
#pragma unroll 1
  for (int i = 0; i < 7; ++i)
    iter256<1024, 1024, false>(Ap, Bp, lds, 2 * i, a.wave, a.wm, a.wn, srcOff, srcOff, a.lnoff0, acc);
  iter256<1024, 1024, true>(Ap, Bp, lds, 14, a.wave, a.wm, a.wn, srcOff, srcOff, a.lnoff0, acc);

  // epilogue: bias + bf16 store; nj innermost -> 4 consecutive stores per line.
  int colb = a.ln15, rowq = (a.ln >> 4) * 4;
  int colbase = tn * 256 + a.wn * 64 + colb;
  float bias[4];
#pragma unroll
  for (int nj = 0; nj < 4; ++nj) bias[nj] = bcat[colbase + nj * 16];
#pragma unroll
  for (int mi = 0; mi < 8; ++mi) {
    int row = tm * 256 + a.wm * 128 + mi * 16 + rowq;
#pragma unroll
    for (int r = 0; r < 4; ++r) {
      ushort* qrow = QK + (size_t)(row + r) * NQK;
#pragma unroll
      for (int nj = 0; nj < 4; ++nj)
        qrow[colbase + nj * 16] = f2bf(acc[mi][nj][r] + bias[nj]);
    }
  }
}

// ------------------- FUSED: S = Q*K^T (causal, 144 blk) + V proj (256 blk)
// l < 144: S-tile (t = l%36 triangle, b = l/36); else V-tile (v = l-144,
// tn = v&7 over HEAD/256, tmv = v>>3 over 8192/256). S first (longest),
// V backfills the 112 idle CUs.
__global__ __launch_bounds__(512) void gemm_sv(const ushort* __restrict__ QK,
                                               const ushort* __restrict__ xbf,
                                               const ushort* __restrict__ WtT,
                                               const float* __restrict__ bcat,
                                               float* __restrict__ S,
                                               ushort* __restrict__ Vt) {
  __shared__ __align__(16) char lds[131072];
  int l = blockIdx.x;
  Addr256 a = addr256();
  floatx4 acc[8][4];
#pragma unroll
  for (int i = 0; i < 8; ++i)
#pragma unroll
    for (int j = 0; j < 4; ++j) acc[i][j] = (floatx4){0.f, 0.f, 0.f, 0.f};

  if (l < 144) {
    // ---------------- S branch (r7 gemm_s256) ----------------
    int t = l % 36, b = l / 36;
    int tm = (int)((sqrtf(8.f * t + 1.f) - 1.f) * 0.5f);
    while ((tm + 1) * (tm + 2) / 2 <= t) ++tm;
    while (tm * (tm + 1) / 2 > t) --tm;
    int tn = t - tm * (tm + 1) / 2;
    int srcOff = srcOff256<NQK>(a.wave, a.ln);
    const ushort* Ap = QK + (size_t)b * T_ * NQK + (size_t)tm * 256 * NQK;         // Q rows
    const ushort* Bp = QK + (size_t)b * T_ * NQK + (size_t)tn * 256 * NQK + 2048;  // K rows
    prologue256<NQK, NQK>(Ap, Bp, lds, a.wave, srcOff, srcOff);
#pragma unroll 1
    for (int i = 0; i < 15; ++i)
      iter256<NQK, NQK, false>(Ap, Bp, lds, 2 * i, a.wave, a.wm, a.wn, srcOff, srcOff, a.lnoff0, acc);
    iter256<NQK, NQK, true>(Ap, Bp, lds, 30, a.wave, a.wm, a.wn, srcOff, srcOff, a.lnoff0, acc);

    float* Sb = S + (size_t)b * T_ * T_;
    int colb = a.ln15, rowq = (a.ln >> 4) * 4;
    int colbase = tn * 256 + a.wn * 64 + colb;
#pragma unroll
    for (int mi = 0; mi < 8; ++mi) {
      int row = tm * 256 + a.wm * 128 + mi * 16 + rowq;
#pragma unroll
      for (int r = 0; r < 4; ++r) {
        float* srow = Sb + (size_t)(row + r) * T_;
#pragma unroll
        for (int nj = 0; nj < 4; ++nj)
          srow[colbase + nj * 16] = acc[mi][nj][r] * SCALE;
      }
    }
  } else {
    // ---------------- V branch (256^2 core + LDS transpose) ----------------
    int v = l - 144;
    int tn = v & 7, tmv = v >> 3;                  // tn over HEAD/256, tmv over 8192/256
    int srcOff = srcOff256<1024>(a.wave, a.ln);
    const ushort* Ap = xbf + (size_t)tmv * 256 * 1024;
    const ushort* Bp = WtT + (size_t)(4096 + tn * 256) * 1024;
    prologue256<1024, 1024>(Ap, Bp, lds, a.wave, srcOff, srcOff);
#pragma unroll 1
    for (int i = 0; i < 7; ++i)
      iter256<1024, 1024, false>(Ap, Bp, lds, 2 * i, a.wave, a.wm, a.wn, srcOff, srcOff, a.lnoff0, acc);
    iter256<1024, 1024, true>(Ap, Bp, lds, 14, a.wave, a.wm, a.wn, srcOff, srcOff, a.lnoff0, acc);

    // write acc (bias + f2bf) into LDS transposed [h][s], 256x512B (=128KiB);
    // swizzle: phys = h*512 + ((s*2) ^ ((h&31)<<4))  (write conflict-free).
    // K-loop's final BARX ordered all LDS reads before this overwrite.
#pragma unroll
    for (int nj = 0; nj < 4; ++nj) {
      int h = a.wn * 64 + nj * 16 + a.ln15;
      float bv = bcat[4096 + tn * 256 + h];
      int xr = (h & 31) << 4;
#pragma unroll
      for (int mi = 0; mi < 8; ++mi) {
        int s0 = a.wm * 128 + mi * 16 + (a.ln >> 4) * 4;
        ushort4 o4;
        o4.x = f2bf(acc[mi][nj][0] + bv);
        o4.y = f2bf(acc[mi][nj][1] + bv);
        o4.z = f2bf(acc[mi][nj][2] + bv);
        o4.w = f2bf(acc[mi][nj][3] + bv);
        *(ushort4*)(lds + h * 512 + ((s0 * 2) ^ xr)) = o4;
      }
    }
    __syncthreads();
    // read rows of [h][s], store coalesced into Vt[b][h_g][s_g]
    int tid = threadIdx.x;
    int b = tmv >> 3, sbase = (tmv & 7) * 256;
    int hr = tid >> 5;                 // 0..15
    int sc16 = tid & 31;               // 16B slot within 512B row
#pragma unroll
    for (int it = 0; it < 16; ++it) {
      int h = it * 16 + hr;
      ushortx8 vv = *(const ushortx8*)(lds + h * 512 + ((sc16 * 16) ^ ((h & 31) << 4)));
      *(ushortx8*)(Vt + ((size_t)b * T_ + tn * 256 + h) * T_ + sbase + sc16 * 8) = vv;
    }
  }
}

// ------------------------------------------------ GEMM: O = P*V (causal, 256)
__global__ __launch_bounds__(512) void gemm_o256(const ushort* __restrict__ P,
                                                 const ushort* __restrict__ Vt,
                                                 float* __restrict__ O) {
  int tn = blockIdx.x, tm = 7 - blockIdx.y, b = blockIdx.z;  // longest-first
  __shared__ __align__(16) char lds[131072];
  Addr256 a = addr256();
  int srcOff = srcOff256<T_>(a.wave, a.ln);
  const ushort* Ap = P + (size_t)b * T_ * T_ + (size_t)tm * 256 * T_;
  const ushort* Bp = Vt + (size_t)b * T_ * T_ + (size_t)tn * 256 * T_;
  floatx4 acc[8][4];
#pragma unroll
  for (int i = 0; i < 8; ++i)
#pragma unroll
    for (int j = 0; j < 4; ++j) acc[i][j] = (floatx4){0.f, 0.f, 0.f, 0.f};

  int niter = (tm + 1) * 2;        // k_end = (tm+1)*256 = niter*128
  prologue256<T_, T_>(Ap, Bp, lds, a.wave, srcOff, srcOff);
#pragma unroll 1
  for (int i = 0; i < niter - 1; ++i)
    iter256<T_, T_, false>(Ap, Bp, lds, 2 * i, a.wave, a.wm, a.wn, srcOff, srcOff, a.lnoff0, acc);
  iter256<T_, T_, true>(Ap, Bp, lds, 2 * (niter - 1), a.wave, a.wm, a.wn, srcOff, srcOff, a.lnoff0, acc);

  float* Ob = O + (size_t)b * T_ * T_;
  int colb = a.ln15, rowq = (a.ln >> 4) * 4;
  int colbase = tn * 256 + a.wn * 64 + colb;
#pragma unroll
  for (int mi = 0; mi < 8; ++mi) {
    int row = tm * 256 + a.wm * 128 + mi * 16 + rowq;
#pragma unroll
    for (int r = 0; r < 4; ++r) {
      float* orow = Ob + (size_t)(row + r) * T_;
#pragma unroll
      for (int nj = 0; nj < 4; ++nj)
        orow[colbase + nj * 16] = acc[mi][nj][r];
    }
  }
}

// ------------------------------------------------------------ causal softmax
__global__ __launch_bounds__(256) void softmax_causal(const float* __restrict__ S,
                                                      ushort* __restrict__ P) {
  int t = blockIdx.x, b = blockIdx.y;
  int tid = threadIdx.x;
  const float* srow = S + ((size_t)b * T_ + t) * T_;
  ushort* prow = P + ((size_t)b * T_ + t) * T_;
  int band = ((t >> 8) + 1) << 8;    // round_up(t+1, 256) == gemm_o256 k_end
  float xv[8];
  float m = -INFINITY;
#pragma unroll
  for (int c = 0; c < 2; ++c) {
    int s0 = c * 1024 + tid * 4;
    float* xs = xv + c * 4;
    if (s0 < band) {
      float4 v = *(const float4*)(srow + s0);
      xs[0] = (s0 + 0 <= t) ? v.x : -INFINITY;  // scale applied in gemm_s
      xs[1] = (s0 + 1 <= t) ? v.y : -INFINITY;
      xs[2] = (s0 + 2 <= t) ? v.z : -INFINITY;
      xs[3] = (s0 + 3 <= t) ? v.w : -INFINITY;
      m = fmaxf(fmaxf(fmaxf(xs[0], xs[1]), fmaxf(xs[2], xs[3])), m);
    } else {
      xs[0] = xs[1] = xs[2] = xs[3] = -INFINITY;
    }
  }
  __shared__ float sm4[4];
  int wid = tid >> 6, ln = tid & 63;
#pragma unroll
  for (int o = 32; o; o >>= 1) m = fmaxf(m, __shfl_xor(m, o));
  if (ln == 0) sm4[wid] = m;
  __syncthreads();
  m = fmaxf(fmaxf(sm4[0], sm4[1]), fmaxf(sm4[2], sm4[3]));
  __syncthreads();
  float sum = 0.f;
#pragma unroll
  for (int k = 0; k < 8; ++k) { xv[k] = __expf(xv[k] - m); sum += xv[k]; }
#pragma unroll
  for (int o = 32; o; o >>= 1) sum += __shfl_xor(sum, o);
  if (ln == 0) sm4[wid] = sum;
  __syncthreads();
  sum = sm4[0] + sm4[1] + sm4[2] + sm4[3];
  float inv = 1.0f / sum;
#pragma unroll
  for (int c = 0; c < 2; ++c) {
    int s0 = c * 1024 + tid * 4;
    if (s0 < band) {
      ushort4 o4;
      o4.x = f2bf(xv[c * 4 + 0] * inv);
      o4.y = f2bf(xv[c * 4 + 1] * inv);
      o4.z = f2bf(xv[c * 4 + 2] * inv);
      o4.w = f2bf(xv[c * 4 + 3] * inv);
      *(ushort4*)(prow + s0) = o4;
    }
  }
}

// ---------------------------------------------------------------- launcher
extern "C" void kernel_launch(void* const* d_in, const int* in_sizes, int n_in,
                              void* d_out, int out_size, void* d_ws, size_t ws_size,
                              hipStream_t stream) {
  (void)in_sizes; (void)n_in; (void)out_size; (void)ws_size;
  const float* x  = (const float*)d_in[0];
  const float* Wq = (const float*)d_in[1];
  const float* bq = (const float*)d_in[2];
  const float* Wk = (const float*)d_in[3];
  const float* bk = (const float*)d_in[4];
  const float* Wv = (const float*)d_in[5];
  const float* bv = (const float*)d_in[6];

  char* ws = (char*)d_ws;
  ushort* xbf  = (ushort*)(ws + 0);           // 16,777,216 B
  ushort* WtT  = (ushort*)(ws + 16777216);    // 12,582,912 B
  float*  bcat = (float*) (ws + 29360128);    //     24,576 B
  ushort* QK   = (ushort*)(ws + 29384704);    // 67,108,864 B  [8192][4096]
  ushort* P    = (ushort*)(ws + 96493568);    // 33,554,432 B
  ushort* Vt   = (ushort*)(ws + 130048000);   // 33,554,432 B  (end ~156 MiB)

  float* S = (float*)d_out;   // S scratch lives in d_out, later overwritten by O
  float* O = (float*)d_out;

  cast_x_kernel  <<<8192, 256, 0, stream>>>(x, xbf);
  wcast_t_kernel <<<dim3(32, 192), dim3(32, 8), 0, stream>>>(Wq, Wk, Wv, WtT);
  bias_cat_kernel<<<24, 256, 0, stream>>>(bq, bk, bv, bcat);
  gemm_qk256     <<<dim3(32, 16), 512, 0, stream>>>(xbf, WtT, bcat, QK);
  gemm_sv        <<<400, 512, 0, stream>>>(QK, xbf, WtT, bcat, S, Vt);
  softmax_causal <<<dim3(2048, 4), 256, 0, stream>>>(S, P);
  gemm_o256      <<<dim3(8, 8, 4), 512, 0, stream>>>(P, Vt, O);
}